// Round 12
// baseline (236.545 us; speedup 1.0000x reference)
//
#include <hip/hip_runtime.h>

#define TT 25000
#define BB 2
#define CC 128
#define NN (BB*TT)   // 50000 nodes
#define NB ((NN + 255) / 256)  // 196 scan blocks

typedef __attribute__((ext_vector_type(8))) short bf16x8;
typedef __attribute__((ext_vector_type(4))) float f32x4;

__device__ inline unsigned short f2bf(float f) {
    unsigned int u = __float_as_uint(f);
    u += 0x7FFF + ((u >> 16) & 1);          // round-to-nearest-even
    return (unsigned short)(u >> 16);
}
__device__ inline float bfhi(unsigned int v) { return __uint_as_float(v << 16); }
__device__ inline float bflo(unsigned int v) { return __uint_as_float(v & 0xFFFF0000u); }

// ---------------- degree count + per-edge sequence number ----------------
__global__ __launch_bounds__(256) void k_deg(const int* __restrict__ dst, int E,
                                             int* __restrict__ deg,
                                             int* __restrict__ eseq) {
    int base = blockIdx.x * 1024 + threadIdx.x;
    int d[4]; bool ok[4];
#pragma unroll
    for (int u = 0; u < 4; ++u) {
        int i = base + u * 256;
        ok[u] = (i < E);
        d[u] = ok[u] ? dst[i] : 0;
    }
#pragma unroll
    for (int u = 0; u < 4; ++u)
        if (ok[u]) eseq[base + u * 256] = atomicAdd(&deg[d[u]], 1);
}

// ---------------- scan pass 1: per-block sums ----------------
__global__ __launch_bounds__(256) void k_bsum(const int* __restrict__ deg,
                                              int* __restrict__ bsum) {
    __shared__ int red[256];
    int tid = threadIdx.x;
    int i = blockIdx.x * 256 + tid;
    red[tid] = (i < NN) ? deg[i] : 0;
    __syncthreads();
#pragma unroll
    for (int o = 128; o > 0; o >>= 1) {
        if (tid < o) red[tid] += red[tid + o];
        __syncthreads();
    }
    if (tid == 0) bsum[blockIdx.x] = red[0];
}

// ---------------- scan pass 2: block prefix + local scan + dinv ----------------
__global__ __launch_bounds__(256) void k_scan2(const int* __restrict__ deg,
                                               const int* __restrict__ bsum,
                                               int* __restrict__ off,
                                               float* __restrict__ dinv) {
    __shared__ int part[256];
    __shared__ int bpref;
    int tid = threadIdx.x;
    int i = blockIdx.x * 256 + tid;

    part[tid] = (tid < NB && tid < blockIdx.x) ? bsum[tid] : 0;
    __syncthreads();
#pragma unroll
    for (int o = 128; o > 0; o >>= 1) {
        if (tid < o) part[tid] += part[tid + o];
        __syncthreads();
    }
    if (tid == 0) bpref = part[0];
    __syncthreads();
    int base = bpref;
    __syncthreads();

    int v = (i < NN) ? deg[i] : 0;
    part[tid] = v;
    __syncthreads();
#pragma unroll
    for (int o = 1; o < 256; o <<= 1) {
        int u = (tid >= o) ? part[tid - o] : 0;
        __syncthreads();
        part[tid] += u;
        __syncthreads();
    }
    int incl = part[tid];
    if (i < NN) {
        off[i]  = base + incl - v;                  // exclusive
        dinv[i] = rsqrtf((float)(v + 1));
    }
    if (i == NN - 1) off[NN] = base + incl;         // == E
}

// ---------------- CSR fill: atomic-free scatter ----------------
__global__ __launch_bounds__(256) void k_fill(const int* __restrict__ src,
                                              const int* __restrict__ dst, int E,
                                              const int* __restrict__ off,
                                              const int* __restrict__ eseq,
                                              int* __restrict__ csr_src) {
    int i = blockIdx.x * blockDim.x + threadIdx.x;
    if (i < E) {
        int d = dst[i];
        csr_src[off[d] + eseq[i]] = src[i];
    }
}

// ---------------- MFMA GEMM: 64 nodes x 128 oc per block, bf16 in/out ----------------
// h' = dinv[n]*x@W, stored CHANNEL-SPLIT: hp[pass][n][32ch], pass = ch/32.
__global__ __launch_bounds__(256) void k_gemm(const float* __restrict__ x,
                                              const float* __restrict__ W,
                                              const float* __restrict__ dinv,
                                              unsigned short* __restrict__ h) {
    __shared__ __align__(16) unsigned short a_lds[4][4][64][8];  // 16 KB
    __shared__ __align__(16) unsigned short b_lds[8][4][64][8];  // 32 KB
    int tid = threadIdx.x;
    int n0 = blockIdx.x * 64;

    // ---- stage A (x -> bf16, fragment order) ----
    {
        int m = tid & 63;
        int n = n0 + m;
        bool ok = (n < NN);
        int b = 0, t = 0;
        if (ok) { b = n / TT; t = n - b * TT; }
        const float* xp = x + ((size_t)b * CC) * TT + t;
        int mt = m >> 4, lm = m & 15;
#pragma unroll
        for (int p = 0; p < 4; ++p) {
            int kg = (tid >> 6) + p * 4;            // 0..15, wave-uniform
            unsigned short tmp[8];
#pragma unroll
            for (int j = 0; j < 8; ++j) {
                float v = ok ? xp[(size_t)(kg * 8 + j) * TT] : 0.f;
                tmp[j] = f2bf(v);
            }
            int kk = kg >> 2, q = kg & 3;
            *(bf16x8*)&a_lds[mt][kk][lm | (q << 4)][0] = *(bf16x8*)tmp;
        }
    }
    // ---- stage B (W -> bf16, fragment order) ----
    {
        int nc = tid & 127;
        int nt = nc >> 4, ln = nc & 15;
#pragma unroll
        for (int p = 0; p < 8; ++p) {
            int kg = (tid >> 7) + p * 2;            // 0..15
            unsigned short tmp[8];
#pragma unroll
            for (int j = 0; j < 8; ++j)
                tmp[j] = f2bf(W[(kg * 8 + j) * CC + nc]);
            int kk = kg >> 2, q = kg & 3;
            *(bf16x8*)&b_lds[nt][kk][ln | (q << 4)][0] = *(bf16x8*)tmp;
        }
    }
    __syncthreads();

    int lane = tid & 63;
    int w = tid >> 6;
    f32x4 acc[8];
#pragma unroll
    for (int nt = 0; nt < 8; ++nt) acc[nt] = (f32x4){0.f, 0.f, 0.f, 0.f};
#pragma unroll
    for (int kk = 0; kk < 4; ++kk) {
        bf16x8 a = *(const bf16x8*)&a_lds[w][kk][lane][0];
#pragma unroll
        for (int nt = 0; nt < 8; ++nt) {
            bf16x8 bb = *(const bf16x8*)&b_lds[nt][kk][lane][0];
            acc[nt] = __builtin_amdgcn_mfma_f32_16x16x32_bf16(a, bb, acc[nt], 0, 0, 0);
        }
    }

    // ---- epilogue: scale by dinv, bf16, store channel-split ----
    int q = lane >> 4, col = lane & 15;
    int nodebase = n0 + w * 16 + q * 4;
    float di[4];
#pragma unroll
    for (int r = 0; r < 4; ++r) {
        int nn = nodebase + r;
        di[r] = (nn < NN) ? dinv[nn] : 0.f;
    }
#pragma unroll
    for (int nt = 0; nt < 8; ++nt) {
        size_t pbase = (size_t)(nt >> 1) * ((size_t)NN * 32);
#pragma unroll
        for (int r = 0; r < 4; ++r) {
            int nn = nodebase + r;
            if (nn < NN)
                h[pbase + (size_t)nn * 32 + (nt & 1) * 16 + col] = f2bf(di[r] * acc[nt][r]);
        }
    }
}

// ---------------- aggregation pass: 32 channels, L2-resident 3.2MB sub-table ----
// wave = node; lane: sub = lane&15 (uint, 2ch), quarter = lane>>4 (edge slot).
// One gather instr covers 4 edges (4 x 64B rows). Cross-quarter shfl_xor reduce.
__global__ __launch_bounds__(256) void k_aggp(const unsigned int* __restrict__ hp,
                                              const int* __restrict__ off,
                                              const int* __restrict__ csr_src,
                                              const float* __restrict__ dinv,
                                              const float* __restrict__ bias,
                                              unsigned int* __restrict__ agg16,
                                              int pass) {
    int lane = threadIdx.x & 63;
    int w    = threadIdx.x >> 6;
    int n    = blockIdx.x * 4 + w;
    if (n >= NN) return;
    int sub = lane & 15;
    int quarter = lane >> 4;
    float ax = 0.f, ay = 0.f;
    int e0 = off[n], e1 = off[n + 1];

    for (int c0 = e0; c0 < e1; c0 += 64) {
        int cnt = e1 - c0; if (cnt > 64) cnt = 64;
        int li = lane < cnt ? lane : cnt - 1;
        int iv = csr_src[c0 + li];                  // up to 64 indices, one load
        for (int j = 0; j < cnt; j += 16) {
            unsigned int v[4]; bool act[4];
#pragma unroll
            for (int u = 0; u < 4; ++u) {
                int ei = j + u * 4 + quarter;
                act[u] = (ei < cnt);
                int s = __shfl(iv, act[u] ? ei : 0, 64);
                v[u] = hp[(size_t)s * 16 + sub];
            }
#pragma unroll
            for (int u = 0; u < 4; ++u) {
                if (act[u]) { ax += bfhi(v[u]); ay += bflo(v[u]); }
            }
        }
    }
    // reduce across quarters (different edges, same channels)
    ax += __shfl_xor(ax, 16, 64);  ay += __shfl_xor(ay, 16, 64);
    ax += __shfl_xor(ax, 32, 64);  ay += __shfl_xor(ay, 32, 64);

    // self loop
    unsigned int hv = hp[(size_t)n * 16 + sub];
    ax += bfhi(hv); ay += bflo(hv);

    float di = dinv[n];
    float2 bb = ((const float2*)bias)[pass * 16 + sub];
    float rx = fmaxf(fmaf(di, ax, bb.x), 0.f);
    float ry = fmaxf(fmaf(di, ay, bb.y), 0.f);
    if (quarter == 0) {
        unsigned int packed = (unsigned int)f2bf(rx) | ((unsigned int)f2bf(ry) << 16);
        agg16[(size_t)n * 64 + pass * 16 + sub] = packed;
    }
}

// ---------------- transpose: agg16 [n][64 uint(2ch)] -> out [b][ch][t] fp32 ----
__global__ void k_trans(const unsigned int* __restrict__ agg16, float* __restrict__ out) {
    __shared__ float tile[32][65];                  // [t][ch]
    int t0 = blockIdx.x * 32;
    int p0 = blockIdx.y * 32;                       // pair offset (32 pairs = 64 ch)
    int b  = blockIdx.z;
    int tx = threadIdx.x, ty = threadIdx.y;         // 32 x 8
#pragma unroll
    for (int i = 0; i < 4; ++i) {
        int t = t0 + ty + i * 8;
        if (t < TT) {
            unsigned int u = agg16[(size_t)(b * TT + t) * 64 + p0 + tx];
            tile[ty + i * 8][2 * tx]     = bfhi(u);
            tile[ty + i * 8][2 * tx + 1] = bflo(u);
        }
    }
    __syncthreads();
    int t = t0 + tx;
    if (t < TT) {
#pragma unroll
        for (int i = 0; i < 8; ++i) {
            int ch = ty + i * 8;                    // 0..63
            out[((size_t)b * CC + 2 * p0 + ch) * TT + t] = tile[tx][ch];
        }
    }
}

extern "C" void kernel_launch(void* const* d_in, const int* in_sizes, int n_in,
                              void* d_out, int out_size, void* d_ws, size_t ws_size,
                              hipStream_t stream) {
    const float* x    = (const float*)d_in[0];
    const float* W    = (const float*)d_in[1];
    const float* bias = (const float*)d_in[2];
    const int*   ei   = (const int*)d_in[3];
    int E = in_sizes[3] / 2;
    const int* src = ei;
    const int* dst = ei + E;
    float* out = (float*)d_out;

    char* ws = (char*)d_ws;
    size_t o = 0;
    unsigned short* h = (unsigned short*)(ws + o); o += (size_t)NN * CC * 2;  // 12.8 MB, 4 pass tables
    unsigned int* agg16 = (unsigned int*)(ws + o); o += (size_t)NN * 64 * 4;  // 12.8 MB
    int*   deg  = (int*)  (ws + o); o += (size_t)NN * 4;
    float* dinv = (float*)(ws + o); o += (size_t)NN * 4;
    int*   off  = (int*)  (ws + o); o += (size_t)(NN + 1) * 4 + 12;
    int*   bsum = (int*)  (ws + o); o += (size_t)((NB + 3) & ~3) * 4;
    int*   eseq = (int*)  (ws + o); o += (size_t)E * 4;
    int*   csrs = (int*)  (ws + o); o += (size_t)E * 4;

    hipMemsetAsync(deg, 0, (size_t)NN * 4, stream);

    k_deg  <<<(E + 1023) / 1024, 256, 0, stream>>>(dst, E, deg, eseq);
    k_bsum <<<NB, 256, 0, stream>>>(deg, bsum);
    k_scan2<<<NB, 256, 0, stream>>>(deg, bsum, off, dinv);
    k_fill <<<(E + 255) / 256, 256, 0, stream>>>(src, dst, E, off, eseq, csrs);
    k_gemm <<<(NN + 63) / 64, 256, 0, stream>>>(x, W, dinv, h);
    for (int pass = 0; pass < 4; ++pass) {
        const unsigned int* hp = (const unsigned int*)(h + (size_t)pass * NN * 32);
        k_aggp<<<(NN + 3) / 4, 256, 0, stream>>>(hp, off, csrs, dinv, bias, agg16, pass);
    }
    dim3 tg((TT + 31) / 32, 2, BB);
    k_trans<<<tg, dim3(32, 8), 0, stream>>>(agg16, out);
}

// Round 13
// 190.979 us; speedup vs baseline: 1.2386x; 1.2386x over previous
//
#include <hip/hip_runtime.h>

#define TT 25000
#define BB 2
#define CC 128
#define NN (BB*TT)   // 50000 nodes
#define NB ((NN + 255) / 256)  // 196 scan blocks

typedef __attribute__((ext_vector_type(8))) short bf16x8;
typedef __attribute__((ext_vector_type(4))) float f32x4;

__device__ inline unsigned short f2bf(float f) {
    unsigned int u = __float_as_uint(f);
    u += 0x7FFF + ((u >> 16) & 1);          // round-to-nearest-even
    return (unsigned short)(u >> 16);
}
__device__ inline float bfhi(unsigned int v) { return __uint_as_float(v << 16); }
__device__ inline float bflo(unsigned int v) { return __uint_as_float(v & 0xFFFF0000u); }

// ---------------- degree count + per-edge sequence number ----------------
__global__ __launch_bounds__(256) void k_deg(const int* __restrict__ dst, int E,
                                             int* __restrict__ deg,
                                             int* __restrict__ eseq) {
    int base = blockIdx.x * 1024 + threadIdx.x;
    int d[4]; bool ok[4];
#pragma unroll
    for (int u = 0; u < 4; ++u) {
        int i = base + u * 256;
        ok[u] = (i < E);
        d[u] = ok[u] ? dst[i] : 0;
    }
#pragma unroll
    for (int u = 0; u < 4; ++u)
        if (ok[u]) eseq[base + u * 256] = atomicAdd(&deg[d[u]], 1);
}

// ---------------- scan pass 1: per-block sums ----------------
__global__ __launch_bounds__(256) void k_bsum(const int* __restrict__ deg,
                                              int* __restrict__ bsum) {
    __shared__ int red[256];
    int tid = threadIdx.x;
    int i = blockIdx.x * 256 + tid;
    red[tid] = (i < NN) ? deg[i] : 0;
    __syncthreads();
#pragma unroll
    for (int o = 128; o > 0; o >>= 1) {
        if (tid < o) red[tid] += red[tid + o];
        __syncthreads();
    }
    if (tid == 0) bsum[blockIdx.x] = red[0];
}

// ---------------- scan pass 2: block prefix + local scan + dinv ----------------
__global__ __launch_bounds__(256) void k_scan2(const int* __restrict__ deg,
                                               const int* __restrict__ bsum,
                                               int* __restrict__ off,
                                               float* __restrict__ dinv) {
    __shared__ int part[256];
    __shared__ int bpref;
    int tid = threadIdx.x;
    int i = blockIdx.x * 256 + tid;

    part[tid] = (tid < NB && tid < blockIdx.x) ? bsum[tid] : 0;
    __syncthreads();
#pragma unroll
    for (int o = 128; o > 0; o >>= 1) {
        if (tid < o) part[tid] += part[tid + o];
        __syncthreads();
    }
    if (tid == 0) bpref = part[0];
    __syncthreads();
    int base = bpref;
    __syncthreads();

    int v = (i < NN) ? deg[i] : 0;
    part[tid] = v;
    __syncthreads();
#pragma unroll
    for (int o = 1; o < 256; o <<= 1) {
        int u = (tid >= o) ? part[tid - o] : 0;
        __syncthreads();
        part[tid] += u;
        __syncthreads();
    }
    int incl = part[tid];
    if (i < NN) {
        off[i]  = base + incl - v;                  // exclusive
        dinv[i] = rsqrtf((float)(v + 1));
    }
    if (i == NN - 1) off[NN] = base + incl;         // == E
}

// ---------------- CSR fill: atomic-free scatter ----------------
__global__ __launch_bounds__(256) void k_fill(const int* __restrict__ src,
                                              const int* __restrict__ dst, int E,
                                              const int* __restrict__ off,
                                              const int* __restrict__ eseq,
                                              int* __restrict__ csr_src) {
    int i = blockIdx.x * blockDim.x + threadIdx.x;
    if (i < E) {
        int d = dst[i];
        csr_src[off[d] + eseq[i]] = src[i];
    }
}

// ---------------- MFMA GEMM: 64 nodes x 128 oc per block, bf16 in/out ----------------
// h'[n][oc] = dinv[n] * sum_c x[n][c] * W[c][oc], stored bf16 row-major [n][128].
__global__ __launch_bounds__(256) void k_gemm(const float* __restrict__ x,
                                              const float* __restrict__ W,
                                              const float* __restrict__ dinv,
                                              unsigned short* __restrict__ h) {
    __shared__ __align__(16) unsigned short a_lds[4][4][64][8];  // 16 KB
    __shared__ __align__(16) unsigned short b_lds[8][4][64][8];  // 32 KB
    int tid = threadIdx.x;
    int n0 = blockIdx.x * 64;

    // ---- stage A (x -> bf16, fragment order) ----
    {
        int m = tid & 63;
        int n = n0 + m;
        bool ok = (n < NN);
        int b = 0, t = 0;
        if (ok) { b = n / TT; t = n - b * TT; }
        const float* xp = x + ((size_t)b * CC) * TT + t;
        int mt = m >> 4, lm = m & 15;
#pragma unroll
        for (int p = 0; p < 4; ++p) {
            int kg = (tid >> 6) + p * 4;            // 0..15, wave-uniform
            unsigned short tmp[8];
#pragma unroll
            for (int j = 0; j < 8; ++j) {
                float v = ok ? xp[(size_t)(kg * 8 + j) * TT] : 0.f;
                tmp[j] = f2bf(v);
            }
            int kk = kg >> 2, q = kg & 3;
            *(bf16x8*)&a_lds[mt][kk][lm | (q << 4)][0] = *(bf16x8*)tmp;
        }
    }
    // ---- stage B (W -> bf16, fragment order) ----
    {
        int nc = tid & 127;
        int nt = nc >> 4, ln = nc & 15;
#pragma unroll
        for (int p = 0; p < 8; ++p) {
            int kg = (tid >> 7) + p * 2;            // 0..15
            unsigned short tmp[8];
#pragma unroll
            for (int j = 0; j < 8; ++j)
                tmp[j] = f2bf(W[(kg * 8 + j) * CC + nc]);
            int kk = kg >> 2, q = kg & 3;
            *(bf16x8*)&b_lds[nt][kk][ln | (q << 4)][0] = *(bf16x8*)tmp;
        }
    }
    __syncthreads();

    int lane = tid & 63;
    int w = tid >> 6;
    f32x4 acc[8];
#pragma unroll
    for (int nt = 0; nt < 8; ++nt) acc[nt] = (f32x4){0.f, 0.f, 0.f, 0.f};
#pragma unroll
    for (int kk = 0; kk < 4; ++kk) {
        bf16x8 a = *(const bf16x8*)&a_lds[w][kk][lane][0];
#pragma unroll
        for (int nt = 0; nt < 8; ++nt) {
            bf16x8 bb = *(const bf16x8*)&b_lds[nt][kk][lane][0];
            acc[nt] = __builtin_amdgcn_mfma_f32_16x16x32_bf16(a, bb, acc[nt], 0, 0, 0);
        }
    }

    // ---- epilogue: scale by dinv, bf16, store ----
    int q = lane >> 4, col = lane & 15;
    int nodebase = n0 + w * 16 + q * 4;
    float di[4];
#pragma unroll
    for (int r = 0; r < 4; ++r) {
        int nn = nodebase + r;
        di[r] = (nn < NN) ? dinv[nn] : 0.f;
    }
#pragma unroll
    for (int nt = 0; nt < 8; ++nt) {
#pragma unroll
        for (int r = 0; r < 4; ++r) {
            int nn = nodebase + r;
            if (nn < NN)
                h[(size_t)nn * CC + nt * 16 + col] = f2bf(di[r] * acc[nt][r]);
        }
    }
}

// ---------------- aggregation: one wave per node; vectorized index fetch ----------------
// out_n = dinv[n] * (sum_j h'[s_j] + h'[n]) + bias; written packed bf16 (uint/lane).
__global__ __launch_bounds__(256) void k_agg(const unsigned int* __restrict__ hb,
                                             const int* __restrict__ off,
                                             const int* __restrict__ csr_src,
                                             const float* __restrict__ dinv,
                                             const float* __restrict__ bias,
                                             unsigned int* __restrict__ agg16) {
    int lane = threadIdx.x & 63;
    int w    = threadIdx.x >> 6;
    int n    = blockIdx.x * 4 + w;
    if (n >= NN) return;
    float ax = 0.f, ay = 0.f;
    int e0 = off[n], e1 = off[n + 1];

    for (int c0 = e0; c0 < e1; c0 += 64) {
        int cnt = e1 - c0; if (cnt > 64) cnt = 64;
        int li = lane < cnt ? lane : cnt - 1;
        int iv = csr_src[c0 + li];                  // 64 indices, one coalesced load
        int j = 0;
        for (; j + 16 <= cnt; j += 16) {
            int s[16];
#pragma unroll
            for (int u = 0; u < 16; ++u) s[u] = __shfl(iv, j + u, 64);
            unsigned int v[16];
#pragma unroll
            for (int u = 0; u < 16; ++u) v[u] = hb[(size_t)s[u] * 64 + lane];
#pragma unroll
            for (int u = 0; u < 16; ++u) { ax += bfhi(v[u]); ay += bflo(v[u]); }
        }
        for (; j + 4 <= cnt; j += 4) {
            int s[4];
#pragma unroll
            for (int u = 0; u < 4; ++u) s[u] = __shfl(iv, j + u, 64);
            unsigned int v[4];
#pragma unroll
            for (int u = 0; u < 4; ++u) v[u] = hb[(size_t)s[u] * 64 + lane];
#pragma unroll
            for (int u = 0; u < 4; ++u) { ax += bfhi(v[u]); ay += bflo(v[u]); }
        }
        for (; j < cnt; ++j) {
            int s = __shfl(iv, j, 64);
            unsigned int v = hb[(size_t)s * 64 + lane];
            ax += bfhi(v); ay += bflo(v);
        }
    }

    unsigned int hv = hb[(size_t)n * 64 + lane];    // self loop
    ax += bfhi(hv);
    ay += bflo(hv);
    float di = dinv[n];
    const float2* b2 = (const float2*)bias;
    float2 bb = b2[lane];
    float rx = fmaxf(fmaf(di, ax, bb.x), 0.f);
    float ry = fmaxf(fmaf(di, ay, bb.y), 0.f);
    unsigned int packed = (unsigned int)f2bf(rx) | ((unsigned int)f2bf(ry) << 16);
    agg16[(size_t)n * 64 + lane] = packed;
}

// ---------------- transpose: agg16 [n][64 uint(2ch)] -> out [b][ch][t] fp32 ----
__global__ void k_trans(const unsigned int* __restrict__ agg16, float* __restrict__ out) {
    __shared__ float tile[32][65];                  // [t][ch]
    int t0 = blockIdx.x * 32;
    int p0 = blockIdx.y * 32;                       // pair offset (32 pairs = 64 ch)
    int b  = blockIdx.z;
    int tx = threadIdx.x, ty = threadIdx.y;         // 32 x 8
#pragma unroll
    for (int i = 0; i < 4; ++i) {
        int t = t0 + ty + i * 8;
        if (t < TT) {
            unsigned int u = agg16[(size_t)(b * TT + t) * 64 + p0 + tx];
            tile[ty + i * 8][2 * tx]     = bfhi(u);
            tile[ty + i * 8][2 * tx + 1] = bflo(u);
        }
    }
    __syncthreads();
    int t = t0 + tx;
    if (t < TT) {
#pragma unroll
        for (int i = 0; i < 8; ++i) {
            int ch = ty + i * 8;                    // 0..63
            out[((size_t)b * CC + 2 * p0 + ch) * TT + t] = tile[tx][ch];
        }
    }
}

extern "C" void kernel_launch(void* const* d_in, const int* in_sizes, int n_in,
                              void* d_out, int out_size, void* d_ws, size_t ws_size,
                              hipStream_t stream) {
    const float* x    = (const float*)d_in[0];
    const float* W    = (const float*)d_in[1];
    const float* bias = (const float*)d_in[2];
    const int*   ei   = (const int*)d_in[3];
    int E = in_sizes[3] / 2;
    const int* src = ei;
    const int* dst = ei + E;
    float* out = (float*)d_out;

    char* ws = (char*)d_ws;
    size_t o = 0;
    unsigned short* h = (unsigned short*)(ws + o); o += (size_t)NN * CC * 2;  // 12.8 MB
    unsigned int* agg16 = (unsigned int*)(ws + o); o += (size_t)NN * 64 * 4;  // 12.8 MB
    int*   deg  = (int*)  (ws + o); o += (size_t)NN * 4;
    float* dinv = (float*)(ws + o); o += (size_t)NN * 4;
    int*   off  = (int*)  (ws + o); o += (size_t)(NN + 1) * 4 + 12;
    int*   bsum = (int*)  (ws + o); o += (size_t)((NB + 3) & ~3) * 4;
    int*   eseq = (int*)  (ws + o); o += (size_t)E * 4;
    int*   csrs = (int*)  (ws + o); o += (size_t)E * 4;

    hipMemsetAsync(deg, 0, (size_t)NN * 4, stream);

    k_deg  <<<(E + 1023) / 1024, 256, 0, stream>>>(dst, E, deg, eseq);
    k_bsum <<<NB, 256, 0, stream>>>(deg, bsum);
    k_scan2<<<NB, 256, 0, stream>>>(deg, bsum, off, dinv);
    k_fill <<<(E + 255) / 256, 256, 0, stream>>>(src, dst, E, off, eseq, csrs);
    k_gemm <<<(NN + 63) / 64, 256, 0, stream>>>(x, W, dinv, h);
    k_agg  <<<(NN + 3) / 4, 256, 0, stream>>>((const unsigned int*)h, off, csrs, dinv, bias, agg16);
    dim3 tg((TT + 31) / 32, 2, BB);
    k_trans<<<tg, dim3(32, 8), 0, stream>>>(agg16, out);
}